// Round 1
// baseline (245.681 us; speedup 1.0000x reference)
//
#include <hip/hip_runtime.h>
#include <hip/hip_fp16.h>
#include <stdint.h>

typedef __attribute__((ext_vector_type(4))) float f32x4;
typedef __attribute__((ext_vector_type(8))) short short8;

__device__ __forceinline__ unsigned short f2bf(float f) {
  unsigned int b = __float_as_uint(f);
  b = b + 0x7FFFu + ((b >> 16) & 1u);   // RNE
  return (unsigned short)(b >> 16);
}

#define CE(a, b) { float _lo = fminf((a), (b)), _hi = fmaxf((a), (b)); (a) = _lo; (b) = _hi; }

// Batcher odd-even merge of two ascending sorted 4-lists (x[0..3], x[4..7]) -> sorted 8
__device__ __forceinline__ void merge8(float x[8]) {
  CE(x[0], x[4]); CE(x[1], x[5]); CE(x[2], x[6]); CE(x[3], x[7]);
  CE(x[2], x[4]); CE(x[3], x[5]);
  CE(x[1], x[2]); CE(x[3], x[4]); CE(x[5], x[6]);
}

// ---------------------------------------------------------------------------
// Kernel 1: x (fp32) -> bf16
// ---------------------------------------------------------------------------
__global__ __launch_bounds__(256) void cvt_kernel(const float* __restrict__ x,
                                                  unsigned short* __restrict__ o) {
  int i = blockIdx.x * 256 + threadIdx.x;   // index over float4s
  f32x4 v = ((const f32x4*)x)[i];
  ushort4 u;
  u.x = f2bf(v[0]); u.y = f2bf(v[1]); u.z = f2bf(v[2]); u.w = f2bf(v[3]);
  ((ushort4*)o)[i] = u;
}

// ---------------------------------------------------------------------------
// Kernel 2: per-row NF4 quant+dequant of weight -> bf16, one block per row
// ---------------------------------------------------------------------------
__global__ __launch_bounds__(256) void quant_kernel(const float* __restrict__ W,
                                                    const float* __restrict__ lut,
                                                    unsigned short* __restrict__ qw) {
  const int C = 4096;
  const int row = blockIdx.x;
  const int tid = threadIdx.x;
  const int lane = tid & 63;
  const int wv = tid >> 6;

  __shared__ float s_lutf[16];
  __shared__ float s_luth[16];
  __shared__ float s_red[4][8];
  __shared__ float s_par[4];

  if (tid < 16) {
    float f = lut[tid];
    s_lutf[tid] = f;
    s_luth[tid] = __half2float(__float2half(f));  // fp16-rounded pole, per reference
  }

  // load 16 elements per thread (4x float4, coalesced)
  const f32x4* Wp = (const f32x4*)(W + (size_t)row * C);
  f32x4 v[4];
#pragma unroll
  for (int i = 0; i < 4; ++i) v[i] = Wp[i * 256 + tid];

  // per-thread bottom-4 (ascending) and top-4 (ascending)
  float bot[4] = {__builtin_inff(), __builtin_inff(), __builtin_inff(), __builtin_inff()};
  float top[4] = {-__builtin_inff(), -__builtin_inff(), -__builtin_inff(), -__builtin_inff()};
#pragma unroll
  for (int i = 0; i < 4; ++i) {
#pragma unroll
    for (int j = 0; j < 4; ++j) {
      float f = v[i][j];
      bot[3] = fminf(bot[3], f); CE(bot[2], bot[3]); CE(bot[1], bot[2]); CE(bot[0], bot[1]);
      top[0] = fmaxf(top[0], f); CE(top[0], top[1]); CE(top[1], top[2]); CE(top[2], top[3]);
    }
  }

  // wave butterfly: merge sorted-4 lists
#pragma unroll
  for (int d = 1; d < 64; d <<= 1) {
    float x[8];
#pragma unroll
    for (int j = 0; j < 4; ++j) { x[j] = bot[j]; x[4 + j] = __shfl_xor(bot[j], d); }
    merge8(x);
#pragma unroll
    for (int j = 0; j < 4; ++j) bot[j] = x[j];
#pragma unroll
    for (int j = 0; j < 4; ++j) { x[j] = top[j]; x[4 + j] = __shfl_xor(top[j], d); }
    merge8(x);
#pragma unroll
    for (int j = 0; j < 4; ++j) top[j] = x[4 + j];
  }

  if (lane == 0) {
#pragma unroll
    for (int j = 0; j < 4; ++j) { s_red[wv][j] = bot[j]; s_red[wv][4 + j] = top[j]; }
  }
  __syncthreads();

  if (tid == 0) {
    float a[8], b[8], m[8];
    // bottoms
#pragma unroll
    for (int j = 0; j < 4; ++j) { a[j] = s_red[0][j]; a[4 + j] = s_red[1][j]; }
    merge8(a);
#pragma unroll
    for (int j = 0; j < 4; ++j) { b[j] = s_red[2][j]; b[4 + j] = s_red[3][j]; }
    merge8(b);
#pragma unroll
    for (int j = 0; j < 4; ++j) { m[j] = a[j]; m[4 + j] = b[j]; }
    merge8(m);
    // m[0..3] = s0..s3 ; quantile 0.0005 -> virtual idx 2.0475
    float lower = m[2] + 0.0475f * (m[3] - m[2]);
    // tops
#pragma unroll
    for (int j = 0; j < 4; ++j) { a[j] = s_red[0][4 + j]; a[4 + j] = s_red[1][4 + j]; }
    merge8(a);
#pragma unroll
    for (int j = 0; j < 4; ++j) { b[j] = s_red[2][4 + j]; b[4 + j] = s_red[3][4 + j]; }
    merge8(b);
#pragma unroll
    for (int j = 0; j < 4; ++j) { m[j] = a[4 + j]; m[4 + j] = b[4 + j]; }
    merge8(m);
    // m[4..7] = s4092..s4095 ; quantile 0.9995 -> virtual idx 4092.9525
    float upper = m[4] + 0.9525f * (m[5] - m[4]);
    s_par[0] = lower; s_par[1] = upper;
  }
  __syncthreads();

  float lower = s_par[0], upper = s_par[1];

  // masked (dense) min/max
  float mn = __builtin_inff(), mx = -__builtin_inff();
#pragma unroll
  for (int i = 0; i < 4; ++i) {
#pragma unroll
    for (int j = 0; j < 4; ++j) {
      float f = v[i][j];
      bool outl = (f <= lower) || (f >= upper);
      if (!outl) { mn = fminf(mn, f); mx = fmaxf(mx, f); }
    }
  }
#pragma unroll
  for (int d = 1; d < 64; d <<= 1) {
    mn = fminf(mn, __shfl_xor(mn, d));
    mx = fmaxf(mx, __shfl_xor(mx, d));
  }
  if (lane == 0) { s_red[wv][0] = mn; s_red[wv][1] = mx; }
  __syncthreads();
  if (tid == 0) {
    float tmn = fminf(fminf(s_red[0][0], s_red[1][0]), fminf(s_red[2][0], s_red[3][0]));
    float tmx = fmaxf(fmaxf(s_red[0][1], s_red[1][1]), fmaxf(s_red[2][1], s_red[3][1]));
    s_par[2] = (tmx + tmn) * 0.5f;   // offset
    s_par[3] = (tmx - tmn) * 0.5f;   // rangeval
  }
  __syncthreads();
  float offset = s_par[2], range = s_par[3];

  // dequant + bf16 store
  unsigned short* outr = qw + (size_t)row * C;
#pragma unroll
  for (int i = 0; i < 4; ++i) {
    ushort4 o;
    unsigned short os[4];
#pragma unroll
    for (int j = 0; j < 4; ++j) {
      float f = v[i][j];
      bool outl = (f <= lower) || (f >= upper);
      float q;
      if (outl) {
        q = f;  // Q=0 pole -> (w-offset)+offset = weight
      } else {
        float ws = (f - offset) / range;
        float best = fabsf(ws - s_lutf[0]);
        int bi = 0;
#pragma unroll
        for (int t = 1; t < 16; ++t) {
          float d2 = fabsf(ws - s_lutf[t]);
          if (d2 < best) { best = d2; bi = t; }
        }
        q = s_luth[bi] * range + offset;
      }
      if (!isfinite(q)) q = 0.0f;   // nan_to_num
      os[j] = f2bf(q);
    }
    o.x = os[0]; o.y = os[1]; o.z = os[2]; o.w = os[3];
    ((ushort4*)outr)[i * 256 + tid] = o;
  }
}

// ---------------------------------------------------------------------------
// Kernel 3: C[M,N] = A[M,K] (bf16) * B[N,K]^T (bf16), fp32 out. m97 structure.
// ---------------------------------------------------------------------------
#define BM 128
#define BN 128
#define BK 32
#define KDIM 4096
#define NDIM 4096
#define NT (KDIM / BK)

__device__ __forceinline__ void gload16(const void* gp, void* lp) {
  __builtin_amdgcn_global_load_lds(
      (const __attribute__((address_space(1))) unsigned int*)(uintptr_t)gp,
      (__attribute__((address_space(3))) unsigned int*)(unsigned int)(uintptr_t)lp,
      16, 0, 0);
}

__global__ __launch_bounds__(256) void gemm_bt(const unsigned short* __restrict__ A,
                                               const unsigned short* __restrict__ B,
                                               float* __restrict__ C) {
  __shared__ __align__(16) unsigned short sA[2][BM * BK];
  __shared__ __align__(16) unsigned short sB[2][BN * BK];

  const int tid = threadIdx.x;
  const int lane = tid & 63;
  const int wv = tid >> 6;
  const int wr = wv >> 1, wc = wv & 1;     // wave tile origin (wr*64, wc*64)
  const int fr = lane & 15, fk = lane >> 4;

  // XCD-aware swizzle (1024 blocks, divisible by 8 -> bijective)
  int bi = blockIdx.x;
  int swz = (bi & 7) * 128 + (bi >> 3);
  int brow = swz >> 5, bcol = swz & 31;

  const unsigned short* Abase = A + (size_t)brow * BM * KDIM;
  const unsigned short* Bbase = B + (size_t)bcol * BN * KDIM;

  f32x4 acc[4][4];
#pragma unroll
  for (int m = 0; m < 4; ++m)
#pragma unroll
    for (int n = 0; n < 4; ++n) acc[m][n] = (f32x4){0.f, 0.f, 0.f, 0.f};

  auto stage = [&](int buf, int kt) {
    int k0 = kt * BK;
#pragma unroll
    for (int it = 0; it < 2; ++it) {
      int Lb = it * 4096 + tid * 16;         // byte offset within the 8KB tile
      int e = Lb >> 1;                       // bf16 element index
      int r = e >> 5, c = e & 31;
      gload16(Abase + (size_t)r * KDIM + k0 + c, (char*)(&sA[buf][0]) + Lb);
      gload16(Bbase + (size_t)r * KDIM + k0 + c, (char*)(&sB[buf][0]) + Lb);
    }
  };

  stage(0, 0);
  __syncthreads();   // drains vmcnt before barrier

  int cur = 0;
  for (int kt = 0; kt < NT; ++kt) {
    if (kt + 1 < NT) stage(cur ^ 1, kt + 1);

    short8 af[4], bf_[4];
#pragma unroll
    for (int m = 0; m < 4; ++m)
      af[m] = *(const short8*)&sA[cur][(wr * 64 + m * 16 + fr) * BK + fk * 8];
#pragma unroll
    for (int n = 0; n < 4; ++n)
      bf_[n] = *(const short8*)&sB[cur][(wc * 64 + n * 16 + fr) * BK + fk * 8];

#pragma unroll
    for (int m = 0; m < 4; ++m)
#pragma unroll
      for (int n = 0; n < 4; ++n)
        acc[m][n] = __builtin_amdgcn_mfma_f32_16x16x32_bf16(af[m], bf_[n], acc[m][n], 0, 0, 0);

    __syncthreads();
    cur ^= 1;
  }

  // epilogue: C/D layout col=lane&15, row=(lane>>4)*4+reg
  const int rbase = brow * BM + wr * 64;
  const int cbase = bcol * BN + wc * 64;
#pragma unroll
  for (int m = 0; m < 4; ++m)
#pragma unroll
    for (int n = 0; n < 4; ++n)
#pragma unroll
      for (int j = 0; j < 4; ++j) {
        int rr = rbase + m * 16 + fk * 4 + j;
        int cc = cbase + n * 16 + fr;
        C[(size_t)rr * NDIM + cc] = acc[m][n][j];
      }
}

// ---------------------------------------------------------------------------
extern "C" void kernel_launch(void* const* d_in, const int* in_sizes, int n_in,
                              void* d_out, int out_size, void* d_ws, size_t ws_size,
                              hipStream_t stream) {
  const float* x = (const float*)d_in[0];
  const float* W = (const float*)d_in[1];
  const float* lut = (const float*)d_in[2];
  float* out = (float*)d_out;

  unsigned short* xb = (unsigned short*)d_ws;                  // 32 MB bf16 x
  unsigned short* qb = xb + (size_t)4096 * 4096;               // 32 MB bf16 qweight

  cvt_kernel<<<4096 * 4096 / 4 / 256, 256, 0, stream>>>(x, xb);
  quant_kernel<<<4096, 256, 0, stream>>>(W, lut, qb);
  gemm_bt<<<1024, 256, 0, stream>>>(xb, qb, out);
}

// Round 2
// 179.110 us; speedup vs baseline: 1.3717x; 1.3717x over previous
//
#include <hip/hip_runtime.h>
#include <hip/hip_fp16.h>
#include <stdint.h>

typedef __attribute__((ext_vector_type(4))) float f32x4;
typedef __attribute__((ext_vector_type(8))) short short8;

__device__ __forceinline__ unsigned short f2bf(float f) {
  unsigned int b = __float_as_uint(f);
  b = b + 0x7FFFu + ((b >> 16) & 1u);   // RNE
  return (unsigned short)(b >> 16);
}

#define CE(a, b) { float _lo = fminf((a), (b)), _hi = fmaxf((a), (b)); (a) = _lo; (b) = _hi; }

// Batcher odd-even merge of two ascending sorted 4-lists (x[0..3], x[4..7]) -> sorted 8
__device__ __forceinline__ void merge8(float x[8]) {
  CE(x[0], x[4]); CE(x[1], x[5]); CE(x[2], x[6]); CE(x[3], x[7]);
  CE(x[2], x[4]); CE(x[3], x[5]);
  CE(x[1], x[2]); CE(x[3], x[4]); CE(x[5], x[6]);
}

// ---------------------------------------------------------------------------
// Fused prep kernel: blocks 0..4095 = per-row NF4 quant+dequant of W -> qb,
//                    blocks 4096..8191 = x fp32 -> bf16 cvt
// ---------------------------------------------------------------------------
__global__ __launch_bounds__(256) void prep_kernel(const float* __restrict__ x,
                                                   const float* __restrict__ W,
                                                   const float* __restrict__ lut,
                                                   unsigned short* __restrict__ xb,
                                                   unsigned short* __restrict__ qb) {
  const int tid = threadIdx.x;

  if (blockIdx.x >= 4096) {
    // ---- cvt path ----
    int b = blockIdx.x - 4096;
    int base = b * 1024 + tid;   // float4 index
#pragma unroll
    for (int it = 0; it < 4; ++it) {
      int i = base + it * 256;
      f32x4 v = ((const f32x4*)x)[i];
      ushort4 u;
      u.x = f2bf(v[0]); u.y = f2bf(v[1]); u.z = f2bf(v[2]); u.w = f2bf(v[3]);
      ((ushort4*)xb)[i] = u;
    }
    return;
  }

  // ---- quant path ----
  const int C = 4096;
  const int row = blockIdx.x;
  const int lane = tid & 63;
  const int wv = tid >> 6;

  __shared__ float s_lutf[16];
  __shared__ float s_luth[16];
  __shared__ float s_red[4][8];
  __shared__ float s_par[4];

  if (tid < 16) {
    float f = lut[tid];
    s_lutf[tid] = f;
    s_luth[tid] = __half2float(__float2half(f));  // fp16-rounded pole, per reference
  }

  const f32x4* Wp = (const f32x4*)(W + (size_t)row * C);
  f32x4 v[4];
#pragma unroll
  for (int i = 0; i < 4; ++i) v[i] = Wp[i * 256 + tid];

  // per-thread bottom-4 (ascending) and top-4 (ascending)
  float bot[4] = {__builtin_inff(), __builtin_inff(), __builtin_inff(), __builtin_inff()};
  float top[4] = {-__builtin_inff(), -__builtin_inff(), -__builtin_inff(), -__builtin_inff()};
#pragma unroll
  for (int i = 0; i < 4; ++i) {
#pragma unroll
    for (int j = 0; j < 4; ++j) {
      float f = v[i][j];
      bot[3] = fminf(bot[3], f); CE(bot[2], bot[3]); CE(bot[1], bot[2]); CE(bot[0], bot[1]);
      top[0] = fmaxf(top[0], f); CE(top[0], top[1]); CE(top[1], top[2]); CE(top[2], top[3]);
    }
  }

#pragma unroll
  for (int d = 1; d < 64; d <<= 1) {
    float xx[8];
#pragma unroll
    for (int j = 0; j < 4; ++j) { xx[j] = bot[j]; xx[4 + j] = __shfl_xor(bot[j], d); }
    merge8(xx);
#pragma unroll
    for (int j = 0; j < 4; ++j) bot[j] = xx[j];
#pragma unroll
    for (int j = 0; j < 4; ++j) { xx[j] = top[j]; xx[4 + j] = __shfl_xor(top[j], d); }
    merge8(xx);
#pragma unroll
    for (int j = 0; j < 4; ++j) top[j] = xx[4 + j];
  }

  if (lane == 0) {
#pragma unroll
    for (int j = 0; j < 4; ++j) { s_red[wv][j] = bot[j]; s_red[wv][4 + j] = top[j]; }
  }
  __syncthreads();

  if (tid == 0) {
    float a[8], b[8], m[8];
#pragma unroll
    for (int j = 0; j < 4; ++j) { a[j] = s_red[0][j]; a[4 + j] = s_red[1][j]; }
    merge8(a);
#pragma unroll
    for (int j = 0; j < 4; ++j) { b[j] = s_red[2][j]; b[4 + j] = s_red[3][j]; }
    merge8(b);
#pragma unroll
    for (int j = 0; j < 4; ++j) { m[j] = a[j]; m[4 + j] = b[j]; }
    merge8(m);
    float lower = m[2] + 0.0475f * (m[3] - m[2]);   // quantile 0.0005 -> idx 2.0475
#pragma unroll
    for (int j = 0; j < 4; ++j) { a[j] = s_red[0][4 + j]; a[4 + j] = s_red[1][4 + j]; }
    merge8(a);
#pragma unroll
    for (int j = 0; j < 4; ++j) { b[j] = s_red[2][4 + j]; b[4 + j] = s_red[3][4 + j]; }
    merge8(b);
#pragma unroll
    for (int j = 0; j < 4; ++j) { m[j] = a[4 + j]; m[4 + j] = b[4 + j]; }
    merge8(m);
    float upper = m[4] + 0.9525f * (m[5] - m[4]);   // quantile 0.9995 -> idx 4092.9525
    s_par[0] = lower; s_par[1] = upper;
  }
  __syncthreads();

  float lower = s_par[0], upper = s_par[1];

  float mn = __builtin_inff(), mx = -__builtin_inff();
#pragma unroll
  for (int i = 0; i < 4; ++i) {
#pragma unroll
    for (int j = 0; j < 4; ++j) {
      float f = v[i][j];
      bool outl = (f <= lower) || (f >= upper);
      if (!outl) { mn = fminf(mn, f); mx = fmaxf(mx, f); }
    }
  }
#pragma unroll
  for (int d = 1; d < 64; d <<= 1) {
    mn = fminf(mn, __shfl_xor(mn, d));
    mx = fmaxf(mx, __shfl_xor(mx, d));
  }
  if (lane == 0) { s_red[wv][0] = mn; s_red[wv][1] = mx; }
  __syncthreads();
  if (tid == 0) {
    float tmn = fminf(fminf(s_red[0][0], s_red[1][0]), fminf(s_red[2][0], s_red[3][0]));
    float tmx = fmaxf(fmaxf(s_red[0][1], s_red[1][1]), fmaxf(s_red[2][1], s_red[3][1]));
    s_par[2] = (tmx + tmn) * 0.5f;   // offset
    s_par[3] = (tmx - tmn) * 0.5f;   // rangeval
  }
  __syncthreads();
  float offset = s_par[2], range = s_par[3];

  unsigned short* outr = qb + (size_t)row * C;
#pragma unroll
  for (int i = 0; i < 4; ++i) {
    ushort4 o;
    unsigned short os[4];
#pragma unroll
    for (int j = 0; j < 4; ++j) {
      float f = v[i][j];
      bool outl = (f <= lower) || (f >= upper);
      float q;
      if (outl) {
        q = f;  // Q=0 pole -> weight passes through
      } else {
        float ws = (f - offset) / range;
        float best = fabsf(ws - s_lutf[0]);
        int bi = 0;
#pragma unroll
        for (int t = 1; t < 16; ++t) {
          float d2 = fabsf(ws - s_lutf[t]);
          if (d2 < best) { best = d2; bi = t; }
        }
        q = s_luth[bi] * range + offset;
      }
      if (!isfinite(q)) q = 0.0f;
      os[j] = f2bf(q);
    }
    o.x = os[0]; o.y = os[1]; o.z = os[2]; o.w = os[3];
    ((ushort4*)outr)[i * 256 + tid] = o;
  }
}

// ---------------------------------------------------------------------------
// GEMM: C[4096,4096] = A[4096,4096]bf16 * B[4096,4096]bf16^T, fp32 out.
// 256x256 tile, 8-phase schedule (T2 swizzle + T3/T4 counted vmcnt + T5).
// ---------------------------------------------------------------------------
#define GK 4096

__device__ __forceinline__ void gload16(const void* gp, void* lp) {
  __builtin_amdgcn_global_load_lds(
      (const __attribute__((address_space(1))) unsigned int*)(uintptr_t)gp,
      (__attribute__((address_space(3))) unsigned int*)(unsigned int)(uintptr_t)lp,
      16, 0, 0);
}

__global__ __launch_bounds__(512, 2) void gemm_bt(const unsigned short* __restrict__ A,
                                                  const unsigned short* __restrict__ B,
                                                  float* __restrict__ C) {
  // 4-slot ring per operand; each slot = one k-half-tile: 256 rows x 32 cols bf16 = 16 KiB
  __shared__ __align__(16) unsigned short sA[4][8192];
  __shared__ __align__(16) unsigned short sB[4][8192];

  const int tid = threadIdx.x;
  const int lane = tid & 63;
  const int wv = tid >> 6;
  const int wm = wv >> 2, wn = wv & 3;       // 2 x 4 wave grid; wave tile 128 x 64
  const int fr = lane & 15, fk = lane >> 4;

  // XCD-aware swizzle: 256 blocks, 256 % 8 == 0 -> bijective
  int bi = blockIdx.x;
  int swz = (bi & 7) * 32 + (bi >> 3);
  int brow = swz >> 4, bcol = swz & 15;

  const unsigned short* Abase = A + (size_t)brow * 256 * GK;
  const unsigned short* Bbase = B + (size_t)bcol * 256 * GK;

  // swizzled k-byte offset for frag reads: XOR byte bits 4-5 with row bits 2-3 (= fr bits 2-3)
  const int fkx = (fk * 16) ^ ((fr & 0xC) << 2);

  f32x4 acc[8][4];
#pragma unroll
  for (int m = 0; m < 8; ++m)
#pragma unroll
    for (int n = 0; n < 4; ++n) acc[m][n] = (f32x4){0.f, 0.f, 0.f, 0.f};

  // stage one operand half-tile (16 KiB) into ring slot; 2 gload_lds per thread.
  // LDS dest linear; global source inverse-swizzled so swizzled reads see (r,c). (rule #21)
  auto stage = [&](const unsigned short* gb, unsigned short (*sbuf)[8192], int slot, int g) {
    int kt = g >> 1;
    if (kt >= 64) kt = 0;                    // tail clamp: keep vmcnt counts uniform
    int k0 = (kt << 6) + ((g & 1) << 5);
#pragma unroll
    for (int l = 0; l < 2; ++l) {
      int Lb = ((wv * 2 + l) << 10) + lane * 16;      // linear byte within 16 KiB slot
      int r = Lb >> 6;
      int cb = (Lb & 63) ^ ((r & 0xC) << 2);          // inverse swizzle (involution)
      gload16(gb + (size_t)r * GK + k0 + (cb >> 1), (char*)&sbuf[slot][0] + Lb);
    }
  };

  // prologue: halves 0,1 -> slots 0,1 ; require half 0 landed before loop
  stage(Abase, sA, 0, 0);
  stage(Bbase, sB, 0, 0);
  stage(Abase, sA, 1, 1);
  stage(Bbase, sB, 1, 1);
  asm volatile("s_waitcnt vmcnt(4)" ::: "memory");
  __builtin_amdgcn_s_barrier();
  __builtin_amdgcn_sched_barrier(0);

#pragma unroll 1
  for (int i = 0; i < 32; ++i) {
#pragma unroll
    for (int q = 0; q < 4; ++q) {
      const char* sAq = (const char*)&sA[q][0];
      const char* sBq = (const char*)&sB[q][0];
      short8 af[4], bfr[4];

      // ---- phase (q,0): m-frags 0-3, all B-frags; stage A-half of g=4i+q+2 ----
#pragma unroll
      for (int m = 0; m < 4; ++m)
        af[m] = *(const short8*)(sAq + (wm * 128 + m * 16 + fr) * 64 + fkx);
#pragma unroll
      for (int n = 0; n < 4; ++n)
        bfr[n] = *(const short8*)(sBq + (wn * 64 + n * 16 + fr) * 64 + fkx);
      stage(Abase, sA, (q + 2) & 3, 4 * i + q + 2);
      __builtin_amdgcn_s_barrier();
      asm volatile("s_waitcnt lgkmcnt(0)" ::: "memory");
      __builtin_amdgcn_sched_barrier(0);
      __builtin_amdgcn_s_setprio(1);
#pragma unroll
      for (int m = 0; m < 4; ++m)
#pragma unroll
        for (int n = 0; n < 4; ++n)
          acc[m][n] = __builtin_amdgcn_mfma_f32_16x16x32_bf16(af[m], bfr[n], acc[m][n], 0, 0, 0);
      __builtin_amdgcn_s_setprio(0);
      __builtin_amdgcn_sched_barrier(0);
      __builtin_amdgcn_s_barrier();

      // ---- phase (q,1): m-frags 4-7, reuse B-frags; stage B-half of g=4i+q+2 ----
#pragma unroll
      for (int m = 0; m < 4; ++m)
        af[m] = *(const short8*)(sAq + (wm * 128 + (4 + m) * 16 + fr) * 64 + fkx);
      stage(Bbase, sB, (q + 2) & 3, 4 * i + q + 2);
      __builtin_amdgcn_s_barrier();
      asm volatile("s_waitcnt lgkmcnt(0)" ::: "memory");
      __builtin_amdgcn_sched_barrier(0);
      __builtin_amdgcn_s_setprio(1);
#pragma unroll
      for (int m = 0; m < 4; ++m)
#pragma unroll
        for (int n = 0; n < 4; ++n)
          acc[4 + m][n] = __builtin_amdgcn_mfma_f32_16x16x32_bf16(af[m], bfr[n], acc[4 + m][n], 0, 0, 0);
      __builtin_amdgcn_s_setprio(0);
      __builtin_amdgcn_sched_barrier(0);
      // pair-end: force next pair's A+B halves landed; keep 2 half-tiles (4 loads) in flight
      asm volatile("s_waitcnt vmcnt(4)" ::: "memory");
      __builtin_amdgcn_s_barrier();
      __builtin_amdgcn_sched_barrier(0);
    }
  }

  // epilogue: verified C/D mapping (round-1): row = m*16 + fk*4 + j, col = n*16 + fr
  const int rbase = brow * 256 + wm * 128;
  const int cbase = bcol * 256 + wn * 64;
#pragma unroll
  for (int m = 0; m < 8; ++m)
#pragma unroll
    for (int n = 0; n < 4; ++n)
#pragma unroll
      for (int j = 0; j < 4; ++j) {
        int rr = rbase + m * 16 + fk * 4 + j;
        int cc = cbase + n * 16 + fr;
        C[(size_t)rr * GK + cc] = acc[m][n][j];
      }
}

// ---------------------------------------------------------------------------
extern "C" void kernel_launch(void* const* d_in, const int* in_sizes, int n_in,
                              void* d_out, int out_size, void* d_ws, size_t ws_size,
                              hipStream_t stream) {
  const float* x = (const float*)d_in[0];
  const float* W = (const float*)d_in[1];
  const float* lut = (const float*)d_in[2];
  float* out = (float*)d_out;

  unsigned short* xb = (unsigned short*)d_ws;                  // 32 MB bf16 x
  unsigned short* qb = xb + (size_t)4096 * 4096;               // 32 MB bf16 qweight

  prep_kernel<<<8192, 256, 0, stream>>>(x, W, lut, xb, qb);
  gemm_bt<<<256, 512, 0, stream>>>(xb, qb, out);
}

// Round 3
// 173.793 us; speedup vs baseline: 1.4136x; 1.0306x over previous
//
#include <hip/hip_runtime.h>
#include <hip/hip_fp16.h>
#include <stdint.h>

typedef __attribute__((ext_vector_type(4))) float f32x4;
typedef __attribute__((ext_vector_type(8))) short short8;

__device__ __forceinline__ unsigned short f2bf(float f) {
  unsigned int b = __float_as_uint(f);
  b = b + 0x7FFFu + ((b >> 16) & 1u);   // RNE
  return (unsigned short)(b >> 16);
}

#define CE(a, b) { float _lo = fminf((a), (b)), _hi = fmaxf((a), (b)); (a) = _lo; (b) = _hi; }

// Batcher odd-even merge of two ascending sorted 4-lists (x[0..3], x[4..7]) -> sorted 8
__device__ __forceinline__ void merge8(float x[8]) {
  CE(x[0], x[4]); CE(x[1], x[5]); CE(x[2], x[6]); CE(x[3], x[7]);
  CE(x[2], x[4]); CE(x[3], x[5]);
  CE(x[1], x[2]); CE(x[3], x[4]); CE(x[5], x[6]);
}

// ---------------------------------------------------------------------------
// Fused prep kernel: blocks 0..4095 = per-row NF4 quant+dequant of W -> qb,
//                    blocks 4096..8191 = x fp32 -> bf16 cvt
// ---------------------------------------------------------------------------
__global__ __launch_bounds__(256) void prep_kernel(const float* __restrict__ x,
                                                   const float* __restrict__ W,
                                                   const float* __restrict__ lut,
                                                   unsigned short* __restrict__ xb,
                                                   unsigned short* __restrict__ qb) {
  const int tid = threadIdx.x;

  if (blockIdx.x >= 4096) {
    // ---- cvt path ----
    int b = blockIdx.x - 4096;
    int base = b * 1024 + tid;   // float4 index
#pragma unroll
    for (int it = 0; it < 4; ++it) {
      int i = base + it * 256;
      f32x4 v = ((const f32x4*)x)[i];
      ushort4 u;
      u.x = f2bf(v[0]); u.y = f2bf(v[1]); u.z = f2bf(v[2]); u.w = f2bf(v[3]);
      ((ushort4*)xb)[i] = u;
    }
    return;
  }

  // ---- quant path ----
  const int C = 4096;
  const int row = blockIdx.x;
  const int lane = tid & 63;
  const int wv = tid >> 6;

  __shared__ float s_lutf[16];
  __shared__ float s_luth[16];
  __shared__ float s_red[4][8];
  __shared__ float s_par[4];

  if (tid < 16) {
    float f = lut[tid];
    s_lutf[tid] = f;
    s_luth[tid] = __half2float(__float2half(f));  // fp16-rounded pole, per reference
  }

  const f32x4* Wp = (const f32x4*)(W + (size_t)row * C);
  f32x4 v[4];
#pragma unroll
  for (int i = 0; i < 4; ++i) v[i] = Wp[i * 256 + tid];

  // per-thread bottom-4 (ascending) and top-4 (ascending)
  float bot[4] = {__builtin_inff(), __builtin_inff(), __builtin_inff(), __builtin_inff()};
  float top[4] = {-__builtin_inff(), -__builtin_inff(), -__builtin_inff(), -__builtin_inff()};
#pragma unroll
  for (int i = 0; i < 4; ++i) {
#pragma unroll
    for (int j = 0; j < 4; ++j) {
      float f = v[i][j];
      bot[3] = fminf(bot[3], f); CE(bot[2], bot[3]); CE(bot[1], bot[2]); CE(bot[0], bot[1]);
      top[0] = fmaxf(top[0], f); CE(top[0], top[1]); CE(top[1], top[2]); CE(top[2], top[3]);
    }
  }

#pragma unroll
  for (int d = 1; d < 64; d <<= 1) {
    float xx[8];
#pragma unroll
    for (int j = 0; j < 4; ++j) { xx[j] = bot[j]; xx[4 + j] = __shfl_xor(bot[j], d); }
    merge8(xx);
#pragma unroll
    for (int j = 0; j < 4; ++j) bot[j] = xx[j];
#pragma unroll
    for (int j = 0; j < 4; ++j) { xx[j] = top[j]; xx[4 + j] = __shfl_xor(top[j], d); }
    merge8(xx);
#pragma unroll
    for (int j = 0; j < 4; ++j) top[j] = xx[4 + j];
  }

  if (lane == 0) {
#pragma unroll
    for (int j = 0; j < 4; ++j) { s_red[wv][j] = bot[j]; s_red[wv][4 + j] = top[j]; }
  }
  __syncthreads();

  if (tid == 0) {
    float a[8], b[8], m[8];
#pragma unroll
    for (int j = 0; j < 4; ++j) { a[j] = s_red[0][j]; a[4 + j] = s_red[1][j]; }
    merge8(a);
#pragma unroll
    for (int j = 0; j < 4; ++j) { b[j] = s_red[2][j]; b[4 + j] = s_red[3][j]; }
    merge8(b);
#pragma unroll
    for (int j = 0; j < 4; ++j) { m[j] = a[j]; m[4 + j] = b[j]; }
    merge8(m);
    float lower = m[2] + 0.0475f * (m[3] - m[2]);   // quantile 0.0005 -> idx 2.0475
#pragma unroll
    for (int j = 0; j < 4; ++j) { a[j] = s_red[0][4 + j]; a[4 + j] = s_red[1][4 + j]; }
    merge8(a);
#pragma unroll
    for (int j = 0; j < 4; ++j) { b[j] = s_red[2][4 + j]; b[4 + j] = s_red[3][4 + j]; }
    merge8(b);
#pragma unroll
    for (int j = 0; j < 4; ++j) { m[j] = a[4 + j]; m[4 + j] = b[4 + j]; }
    merge8(m);
    float upper = m[4] + 0.9525f * (m[5] - m[4]);   // quantile 0.9995 -> idx 4092.9525
    s_par[0] = lower; s_par[1] = upper;
  }
  __syncthreads();

  float lower = s_par[0], upper = s_par[1];

  float mn = __builtin_inff(), mx = -__builtin_inff();
#pragma unroll
  for (int i = 0; i < 4; ++i) {
#pragma unroll
    for (int j = 0; j < 4; ++j) {
      float f = v[i][j];
      bool outl = (f <= lower) || (f >= upper);
      if (!outl) { mn = fminf(mn, f); mx = fmaxf(mx, f); }
    }
  }
#pragma unroll
  for (int d = 1; d < 64; d <<= 1) {
    mn = fminf(mn, __shfl_xor(mn, d));
    mx = fmaxf(mx, __shfl_xor(mx, d));
  }
  if (lane == 0) { s_red[wv][0] = mn; s_red[wv][1] = mx; }
  __syncthreads();
  if (tid == 0) {
    float tmn = fminf(fminf(s_red[0][0], s_red[1][0]), fminf(s_red[2][0], s_red[3][0]));
    float tmx = fmaxf(fmaxf(s_red[0][1], s_red[1][1]), fmaxf(s_red[2][1], s_red[3][1]));
    s_par[2] = (tmx + tmn) * 0.5f;   // offset
    s_par[3] = (tmx - tmn) * 0.5f;   // rangeval
  }
  __syncthreads();
  float offset = s_par[2], range = s_par[3];

  unsigned short* outr = qb + (size_t)row * C;
#pragma unroll
  for (int i = 0; i < 4; ++i) {
    ushort4 o;
    unsigned short os[4];
#pragma unroll
    for (int j = 0; j < 4; ++j) {
      float f = v[i][j];
      bool outl = (f <= lower) || (f >= upper);
      float q;
      if (outl) {
        q = f;  // Q=0 pole -> weight passes through
      } else {
        float ws = (f - offset) / range;
        float best = fabsf(ws - s_lutf[0]);
        int bi = 0;
#pragma unroll
        for (int t = 1; t < 16; ++t) {
          float d2 = fabsf(ws - s_lutf[t]);
          if (d2 < best) { best = d2; bi = t; }
        }
        q = s_luth[bi] * range + offset;
      }
      if (!isfinite(q)) q = 0.0f;
      os[j] = f2bf(q);
    }
    o.x = os[0]; o.y = os[1]; o.z = os[2]; o.w = os[3];
    ((ushort4*)outr)[i * 256 + tid] = o;
  }
}

// ---------------------------------------------------------------------------
// GEMM: C[4096,4096] = A * B^T (bf16 in, fp32 out). m201 port:
// 256x256 tile, BK=64, 8 waves (2Mx4N), LDS = 2 kbuf x 2 half x (A,B) x 16KB,
// st_16x32 swizzle (col-byte bit5 ^= row bit2), 8-phase counted-vmcnt schedule.
// ---------------------------------------------------------------------------
#define GK 4096

__device__ __forceinline__ void gload16(const void* gp, void* lp) {
  __builtin_amdgcn_global_load_lds(
      (const __attribute__((address_space(1))) unsigned int*)(uintptr_t)gp,
      (__attribute__((address_space(3))) unsigned int*)(unsigned int)(uintptr_t)lp,
      16, 0, 0);
}

#define BAR()    __builtin_amdgcn_s_barrier()
#define SCHED0() __builtin_amdgcn_sched_barrier(0)
#define LGKM0()  asm volatile("s_waitcnt lgkmcnt(0)" ::: "memory")
#define VM4()    asm volatile("s_waitcnt vmcnt(4)" ::: "memory")
#define PRIO1()  __builtin_amdgcn_s_setprio(1)
#define PRIO0()  __builtin_amdgcn_s_setprio(0)

__global__ __launch_bounds__(512, 2) void gemm_bt(const unsigned short* __restrict__ A,
                                                  const unsigned short* __restrict__ B,
                                                  float* __restrict__ C) {
  // [kbuf][half][128 rows * 64 cols] bf16 = 16 KiB each; total 128 KiB
  __shared__ __align__(16) unsigned short sA[2][2][8192];
  __shared__ __align__(16) unsigned short sB[2][2][8192];

  const int tid = threadIdx.x;
  const int lane = tid & 63;
  const int wv = tid >> 6;
  const int wm = wv >> 2, wn = wv & 3;       // 2 x 4 wave grid; wave tile 128 x 64
  const int fr = lane & 15, fk = lane >> 4;

  // XCD-aware swizzle: 256 blocks, 256 % 8 == 0 -> bijective
  int bi = blockIdx.x;
  int swz = (bi & 7) * 32 + (bi >> 3);
  int brow = swz >> 4, bcol = swz & 15;

  const unsigned short* Abase = A + (size_t)brow * 256 * GK;
  const unsigned short* Bbase = B + (size_t)bcol * 256 * GK;

  // ds_read swizzled col-byte: (kh*64 + fk*16) ^ ((row>>2)&1)<<5 ; row bit2 == fr bit2
  const int c0 = (fk * 16) ^ (((fr >> 2) & 1) << 5);

  // stage source pre-swizzle: LDS linear pos Lb=(wv*1024+l*8192+lane*16) holds
  // global (row = wv*8+l*64+(lane>>3), colbyte = (lane&7)*16 ^ (rowbit2<<5));
  // rowbit2 == lane bit 5.
  const int srow = lane >> 3;
  const int scolE = (((lane & 7) * 16) ^ (((lane >> 5) & 1) << 5)) >> 1;

  auto stage = [&](const unsigned short* gb, unsigned short* lb, int h, int kt) {
    const unsigned short* g = gb + ((size_t)h * 128) * GK + kt * 64 + scolE;
    char* lc = (char*)lb + wv * 1024 + lane * 16;
#pragma unroll
    for (int l = 0; l < 2; ++l)
      gload16(g + (size_t)(wv * 8 + l * 64 + srow) * GK, lc + l * 8192);
  };

  f32x4 acc[8][4];
#pragma unroll
  for (int m = 0; m < 8; ++m)
#pragma unroll
    for (int n = 0; n < 4; ++n) acc[m][n] = (f32x4){0.f, 0.f, 0.f, 0.f};

  // ---- prologue: A(0) both halves, B(0) both halves, B(1) both halves ----
  stage(Abase, &sA[0][0][0], 0, 0);
  stage(Abase, &sA[0][1][0], 1, 0);
  stage(Bbase, &sB[0][0][0], 0, 0);
  stage(Bbase, &sB[0][1][0], 1, 0);
  stage(Bbase, &sB[1][0][0], 0, 1);
  stage(Bbase, &sB[1][1][0], 1, 1);
  VM4();            // A(0), B(0) landed; B(1) may remain in flight
  BAR();
  SCHED0();

  const int rB = (wn & 1) * 64;        // B local row base within half

#pragma unroll 1
  for (int i = 0; i < 32; ++i) {
    const int ktA1 = 2 * i + 1;                          // A kt1, staged ph1-2, read ph5
    const int ktN0 = (2 * i + 2 < 64) ? 2 * i + 2 : 63;  // next kt0 (B: ph3-4, A: ph5-6)
    const int ktN1 = (2 * i + 3 < 64) ? 2 * i + 3 : 63;  // next kt1 (B: ph7-8)

    short8 af[4][2], bf0[2][2], bf1[2][2];

    // ================= K-tile kt0 (kbuf 0), phases 1-4 =================
    {
      const char* bA = (const char*)&sA[0][wm][0];
      const char* bB = (const char*)&sB[0][wn >> 1][0];

      // -- ph1: read A m0-3 + B n0-1; stage A(kt1,h0) --
#pragma unroll
      for (int m = 0; m < 4; ++m)
#pragma unroll
        for (int kh = 0; kh < 2; ++kh)
          af[m][kh] = *(const short8*)(bA + (m * 16 + fr) * 128 + kh * 64 + c0);
#pragma unroll
      for (int n = 0; n < 2; ++n)
#pragma unroll
        for (int kh = 0; kh < 2; ++kh)
          bf0[n][kh] = *(const short8*)(bB + (rB + n * 16 + fr) * 128 + kh * 64 + c0);
      stage(Abase, &sA[1][0][0], 0, ktA1);
      BAR(); LGKM0(); SCHED0(); PRIO1();
#pragma unroll
      for (int m = 0; m < 4; ++m)
#pragma unroll
        for (int n = 0; n < 2; ++n)
#pragma unroll
          for (int kh = 0; kh < 2; ++kh)
            acc[m][n] = __builtin_amdgcn_mfma_f32_16x16x32_bf16(af[m][kh], bf0[n][kh], acc[m][n], 0, 0, 0);
      PRIO0(); SCHED0(); BAR();

      // -- ph2: read B n2-3; stage A(kt1,h1) --
#pragma unroll
      for (int n = 0; n < 2; ++n)
#pragma unroll
        for (int kh = 0; kh < 2; ++kh)
          bf1[n][kh] = *(const short8*)(bB + (rB + (n + 2) * 16 + fr) * 128 + kh * 64 + c0);
      stage(Abase, &sA[1][1][0], 1, ktA1);
      BAR(); LGKM0(); SCHED0(); PRIO1();
#pragma unroll
      for (int m = 0; m < 4; ++m)
#pragma unroll
        for (int n = 0; n < 2; ++n)
#pragma unroll
          for (int kh = 0; kh < 2; ++kh)
            acc[m][n + 2] = __builtin_amdgcn_mfma_f32_16x16x32_bf16(af[m][kh], bf1[n][kh], acc[m][n + 2], 0, 0, 0);
      PRIO0(); SCHED0(); BAR();

      // -- ph3: read A m4-7; stage B(ktN0,h0) [B kbuf0 dead after ph2 barrier] --
#pragma unroll
      for (int m = 0; m < 4; ++m)
#pragma unroll
        for (int kh = 0; kh < 2; ++kh)
          af[m][kh] = *(const short8*)(bA + ((m + 4) * 16 + fr) * 128 + kh * 64 + c0);
      stage(Bbase, &sB[0][0][0], 0, ktN0);
      BAR(); LGKM0(); SCHED0(); PRIO1();
#pragma unroll
      for (int m = 0; m < 4; ++m)
#pragma unroll
        for (int n = 0; n < 2; ++n)
#pragma unroll
          for (int kh = 0; kh < 2; ++kh)
            acc[m + 4][n + 2] = __builtin_amdgcn_mfma_f32_16x16x32_bf16(af[m][kh], bf1[n][kh], acc[m + 4][n + 2], 0, 0, 0);
      PRIO0(); SCHED0(); BAR();

      // -- ph4: no ds_reads; stage B(ktN0,h1); vmcnt(4) -> A(kt1) landed --
      stage(Bbase, &sB[0][1][0], 1, ktN0);
      BAR(); PRIO1();
#pragma unroll
      for (int m = 0; m < 4; ++m)
#pragma unroll
        for (int n = 0; n < 2; ++n)
#pragma unroll
          for (int kh = 0; kh < 2; ++kh)
            acc[m + 4][n] = __builtin_amdgcn_mfma_f32_16x16x32_bf16(af[m][kh], bf0[n][kh], acc[m + 4][n], 0, 0, 0);
      PRIO0(); SCHED0();
      VM4(); BAR(); SCHED0();
    }

    // ================= K-tile kt1 (kbuf 1), phases 5-8 =================
    {
      const char* bA = (const char*)&sA[1][wm][0];
      const char* bB = (const char*)&sB[1][wn >> 1][0];

      // -- ph5: read A m0-3 + B n0-1; stage A(ktN0,h0) [A kbuf0 dead after ph3] --
#pragma unroll
      for (int m = 0; m < 4; ++m)
#pragma unroll
        for (int kh = 0; kh < 2; ++kh)
          af[m][kh] = *(const short8*)(bA + (m * 16 + fr) * 128 + kh * 64 + c0);
#pragma unroll
      for (int n = 0; n < 2; ++n)
#pragma unroll
        for (int kh = 0; kh < 2; ++kh)
          bf0[n][kh] = *(const short8*)(bB + (rB + n * 16 + fr) * 128 + kh * 64 + c0);
      stage(Abase, &sA[0][0][0], 0, ktN0);
      BAR(); LGKM0(); SCHED0(); PRIO1();
#pragma unroll
      for (int m = 0; m < 4; ++m)
#pragma unroll
        for (int n = 0; n < 2; ++n)
#pragma unroll
          for (int kh = 0; kh < 2; ++kh)
            acc[m][n] = __builtin_amdgcn_mfma_f32_16x16x32_bf16(af[m][kh], bf0[n][kh], acc[m][n], 0, 0, 0);
      PRIO0(); SCHED0(); BAR();

      // -- ph6: read B n2-3; stage A(ktN0,h1) --
#pragma unroll
      for (int n = 0; n < 2; ++n)
#pragma unroll
        for (int kh = 0; kh < 2; ++kh)
          bf1[n][kh] = *(const short8*)(bB + (rB + (n + 2) * 16 + fr) * 128 + kh * 64 + c0);
      stage(Abase, &sA[0][1][0], 1, ktN0);
      BAR(); LGKM0(); SCHED0(); PRIO1();
#pragma unroll
      for (int m = 0; m < 4; ++m)
#pragma unroll
        for (int n = 0; n < 2; ++n)
#pragma unroll
          for (int kh = 0; kh < 2; ++kh)
            acc[m][n + 2] = __builtin_amdgcn_mfma_f32_16x16x32_bf16(af[m][kh], bf1[n][kh], acc[m][n + 2], 0, 0, 0);
      PRIO0(); SCHED0(); BAR();

      // -- ph7: read A m4-7; stage B(ktN1,h0) [B kbuf1 dead after ph6] --
#pragma unroll
      for (int m = 0; m < 4; ++m)
#pragma unroll
        for (int kh = 0; kh < 2; ++kh)
          af[m][kh] = *(const short8*)(bA + ((m + 4) * 16 + fr) * 128 + kh * 64 + c0);
      stage(Bbase, &sB[1][0][0], 0, ktN1);
      BAR(); LGKM0(); SCHED0(); PRIO1();
#pragma unroll
      for (int m = 0; m < 4; ++m)
#pragma unroll
        for (int n = 0; n < 2; ++n)
#pragma unroll
          for (int kh = 0; kh < 2; ++kh)
            acc[m + 4][n + 2] = __builtin_amdgcn_mfma_f32_16x16x32_bf16(af[m][kh], bf1[n][kh], acc[m + 4][n + 2], 0, 0, 0);
      PRIO0(); SCHED0(); BAR();

      // -- ph8: no ds_reads; stage B(ktN1,h1); vmcnt(4) -> A/B(ktN0) landed --
      stage(Bbase, &sB[1][1][0], 1, ktN1);
      BAR(); PRIO1();
#pragma unroll
      for (int m = 0; m < 4; ++m)
#pragma unroll
        for (int n = 0; n < 2; ++n)
#pragma unroll
          for (int kh = 0; kh < 2; ++kh)
            acc[m + 4][n] = __builtin_amdgcn_mfma_f32_16x16x32_bf16(af[m][kh], bf0[n][kh], acc[m + 4][n], 0, 0, 0);
      PRIO0(); SCHED0();
      VM4(); BAR(); SCHED0();
    }
  }

  // epilogue: verified C/D mapping: row = m*16 + fk*4 + j, col = n*16 + fr
  const int rbase = brow * 256 + wm * 128;
  const int cbase = bcol * 256 + wn * 64;
#pragma unroll
  for (int m = 0; m < 8; ++m)
#pragma unroll
    for (int n = 0; n < 4; ++n)
#pragma unroll
      for (int j = 0; j < 4; ++j) {
        int rr = rbase + m * 16 + fk * 4 + j;
        int cc = cbase + n * 16 + fr;
        C[(size_t)rr * GK + cc] = acc[m][n][j];
      }
}

// ---------------------------------------------------------------------------
extern "C" void kernel_launch(void* const* d_in, const int* in_sizes, int n_in,
                              void* d_out, int out_size, void* d_ws, size_t ws_size,
                              hipStream_t stream) {
  const float* x = (const float*)d_in[0];
  const float* W = (const float*)d_in[1];
  const float* lut = (const float*)d_in[2];
  float* out = (float*)d_out;

  unsigned short* xb = (unsigned short*)d_ws;                  // 32 MB bf16 x
  unsigned short* qb = xb + (size_t)4096 * 4096;               // 32 MB bf16 qweight

  prep_kernel<<<8192, 256, 0, stream>>>(x, W, lut, xb, qb);
  gemm_bt<<<256, 512, 0, stream>>>(xb, qb, out);
}

// Round 4
// 166.822 us; speedup vs baseline: 1.4727x; 1.0418x over previous
//
#include <hip/hip_runtime.h>
#include <hip/hip_fp16.h>
#include <stdint.h>

typedef __attribute__((ext_vector_type(4))) float f32x4;
typedef __attribute__((ext_vector_type(8))) short short8;

__device__ __forceinline__ unsigned short f2bf(float f) {
  unsigned int b = __float_as_uint(f);
  b = b + 0x7FFFu + ((b >> 16) & 1u);   // RNE
  return (unsigned short)(b >> 16);
}

#define CE(a, b) { float _lo = fminf((a), (b)), _hi = fmaxf((a), (b)); (a) = _lo; (b) = _hi; }

// Batcher odd-even merge of two ascending sorted 4-lists (x[0..3], x[4..7]) -> sorted 8
__device__ __forceinline__ void merge8(float x[8]) {
  CE(x[0], x[4]); CE(x[1], x[5]); CE(x[2], x[6]); CE(x[3], x[7]);
  CE(x[2], x[4]); CE(x[3], x[5]);
  CE(x[1], x[2]); CE(x[3], x[4]); CE(x[5], x[6]);
}

// ---------------------------------------------------------------------------
// Fused prep kernel: blocks 0..4095 = per-row NF4 quant+dequant of W -> qb,
//                    blocks 4096..8191 = x fp32 -> bf16 cvt
// ---------------------------------------------------------------------------
__global__ __launch_bounds__(256) void prep_kernel(const float* __restrict__ x,
                                                   const float* __restrict__ W,
                                                   const float* __restrict__ lut,
                                                   unsigned short* __restrict__ xb,
                                                   unsigned short* __restrict__ qb) {
  const int tid = threadIdx.x;

  if (blockIdx.x >= 4096) {
    // ---- cvt path ----
    int b = blockIdx.x - 4096;
    int base = b * 1024 + tid;   // float4 index
#pragma unroll
    for (int it = 0; it < 4; ++it) {
      int i = base + it * 256;
      f32x4 v = ((const f32x4*)x)[i];
      ushort4 u;
      u.x = f2bf(v[0]); u.y = f2bf(v[1]); u.z = f2bf(v[2]); u.w = f2bf(v[3]);
      ((ushort4*)xb)[i] = u;
    }
    return;
  }

  // ---- quant path ----
  const int C = 4096;
  const int row = blockIdx.x;
  const int lane = tid & 63;
  const int wv = tid >> 6;

  __shared__ float s_lutf[16];
  __shared__ float s_luth[16];
  __shared__ float s_red[4][8];
  __shared__ float s_par[4];

  if (tid < 16) {
    float f = lut[tid];
    s_lutf[tid] = f;
    s_luth[tid] = __half2float(__float2half(f));  // fp16-rounded pole, per reference
  }

  const f32x4* Wp = (const f32x4*)(W + (size_t)row * C);
  f32x4 v[4];
#pragma unroll
  for (int i = 0; i < 4; ++i) v[i] = Wp[i * 256 + tid];

  // per-thread bottom-4 (ascending) and top-4 (ascending)
  float bot[4] = {__builtin_inff(), __builtin_inff(), __builtin_inff(), __builtin_inff()};
  float top[4] = {-__builtin_inff(), -__builtin_inff(), -__builtin_inff(), -__builtin_inff()};
#pragma unroll
  for (int i = 0; i < 4; ++i) {
#pragma unroll
    for (int j = 0; j < 4; ++j) {
      float f = v[i][j];
      bot[3] = fminf(bot[3], f); CE(bot[2], bot[3]); CE(bot[1], bot[2]); CE(bot[0], bot[1]);
      top[0] = fmaxf(top[0], f); CE(top[0], top[1]); CE(top[1], top[2]); CE(top[2], top[3]);
    }
  }

#pragma unroll
  for (int d = 1; d < 64; d <<= 1) {
    float xx[8];
#pragma unroll
    for (int j = 0; j < 4; ++j) { xx[j] = bot[j]; xx[4 + j] = __shfl_xor(bot[j], d); }
    merge8(xx);
#pragma unroll
    for (int j = 0; j < 4; ++j) bot[j] = xx[j];
#pragma unroll
    for (int j = 0; j < 4; ++j) { xx[j] = top[j]; xx[4 + j] = __shfl_xor(top[j], d); }
    merge8(xx);
#pragma unroll
    for (int j = 0; j < 4; ++j) top[j] = xx[4 + j];
  }

  if (lane == 0) {
#pragma unroll
    for (int j = 0; j < 4; ++j) { s_red[wv][j] = bot[j]; s_red[wv][4 + j] = top[j]; }
  }
  __syncthreads();

  if (tid == 0) {
    float a[8], b[8], m[8];
#pragma unroll
    for (int j = 0; j < 4; ++j) { a[j] = s_red[0][j]; a[4 + j] = s_red[1][j]; }
    merge8(a);
#pragma unroll
    for (int j = 0; j < 4; ++j) { b[j] = s_red[2][j]; b[4 + j] = s_red[3][j]; }
    merge8(b);
#pragma unroll
    for (int j = 0; j < 4; ++j) { m[j] = a[j]; m[4 + j] = b[j]; }
    merge8(m);
    float lower = m[2] + 0.0475f * (m[3] - m[2]);   // quantile 0.0005 -> idx 2.0475
#pragma unroll
    for (int j = 0; j < 4; ++j) { a[j] = s_red[0][4 + j]; a[4 + j] = s_red[1][4 + j]; }
    merge8(a);
#pragma unroll
    for (int j = 0; j < 4; ++j) { b[j] = s_red[2][4 + j]; b[4 + j] = s_red[3][4 + j]; }
    merge8(b);
#pragma unroll
    for (int j = 0; j < 4; ++j) { m[j] = a[4 + j]; m[4 + j] = b[4 + j]; }
    merge8(m);
    float upper = m[4] + 0.9525f * (m[5] - m[4]);   // quantile 0.9995 -> idx 4092.9525
    s_par[0] = lower; s_par[1] = upper;
  }
  __syncthreads();

  float lower = s_par[0], upper = s_par[1];

  float mn = __builtin_inff(), mx = -__builtin_inff();
#pragma unroll
  for (int i = 0; i < 4; ++i) {
#pragma unroll
    for (int j = 0; j < 4; ++j) {
      float f = v[i][j];
      bool outl = (f <= lower) || (f >= upper);
      if (!outl) { mn = fminf(mn, f); mx = fmaxf(mx, f); }
    }
  }
#pragma unroll
  for (int d = 1; d < 64; d <<= 1) {
    mn = fminf(mn, __shfl_xor(mn, d));
    mx = fmaxf(mx, __shfl_xor(mx, d));
  }
  if (lane == 0) { s_red[wv][0] = mn; s_red[wv][1] = mx; }
  __syncthreads();
  if (tid == 0) {
    float tmn = fminf(fminf(s_red[0][0], s_red[1][0]), fminf(s_red[2][0], s_red[3][0]));
    float tmx = fmaxf(fmaxf(s_red[0][1], s_red[1][1]), fmaxf(s_red[2][1], s_red[3][1]));
    s_par[2] = (tmx + tmn) * 0.5f;   // offset
    s_par[3] = (tmx - tmn) * 0.5f;   // rangeval
  }
  __syncthreads();
  float offset = s_par[2], range = s_par[3];

  unsigned short* outr = qb + (size_t)row * C;
#pragma unroll
  for (int i = 0; i < 4; ++i) {
    ushort4 o;
    unsigned short os[4];
#pragma unroll
    for (int j = 0; j < 4; ++j) {
      float f = v[i][j];
      bool outl = (f <= lower) || (f >= upper);
      float q;
      if (outl) {
        q = f;  // Q=0 pole -> weight passes through
      } else {
        float ws = (f - offset) / range;
        float best = fabsf(ws - s_lutf[0]);
        int bi = 0;
#pragma unroll
        for (int t = 1; t < 16; ++t) {
          float d2 = fabsf(ws - s_lutf[t]);
          if (d2 < best) { best = d2; bi = t; }
        }
        q = s_luth[bi] * range + offset;
      }
      if (!isfinite(q)) q = 0.0f;
      os[j] = f2bf(q);
    }
    o.x = os[0]; o.y = os[1]; o.z = os[2]; o.w = os[3];
    ((ushort4*)outr)[i * 256 + tid] = o;
  }
}

// ---------------------------------------------------------------------------
// GEMM: C[4096,4096] = A * B^T (bf16 in, fp32 out). m201 port, round 4:
// 256x256 tile, BK=64, 8 waves (2Mx4N), LDS = 2 kbuf x 2 half x (A,B) x 16KB.
// LDS layout per 16KB half-tile: SUBTILED st_16x32 (m201 exact):
//   lds_byte(row,kbyte) = (row>>4)*2048 + (kbyte>>6)*1024 + (row&15)*64
//                         + ((kbyte&63) ^ ((row&8)<<2))
// 64B row stride -> row parity alternates bank halves; XOR row-bit-3 into
// byte-bit-5 -> <=2 lanes/bank per ds_read_b128 (free, m136).
// Schedule identical to round 3 (8-phase, counted vmcnt(4), setprio).
// ---------------------------------------------------------------------------
#define GK 4096

__device__ __forceinline__ void gload16(const void* gp, void* lp) {
  __builtin_amdgcn_global_load_lds(
      (const __attribute__((address_space(1))) unsigned int*)(uintptr_t)gp,
      (__attribute__((address_space(3))) unsigned int*)(unsigned int)(uintptr_t)lp,
      16, 0, 0);
}

#define BAR()    __builtin_amdgcn_s_barrier()
#define SCHED0() __builtin_amdgcn_sched_barrier(0)
#define LGKM0()  asm volatile("s_waitcnt lgkmcnt(0)" ::: "memory")
#define VM4()    asm volatile("s_waitcnt vmcnt(4)" ::: "memory")
#define PRIO1()  __builtin_amdgcn_s_setprio(1)
#define PRIO0()  __builtin_amdgcn_s_setprio(0)

__global__ __launch_bounds__(512, 2) void gemm_bt(const unsigned short* __restrict__ A,
                                                  const unsigned short* __restrict__ B,
                                                  float* __restrict__ C) {
  // [kbuf][half][16KB half-tile] ; total 128 KiB
  __shared__ __align__(16) unsigned short sA[2][2][8192];
  __shared__ __align__(16) unsigned short sB[2][2][8192];

  const int tid = threadIdx.x;
  const int lane = tid & 63;
  const int wv = tid >> 6;
  const int wm = wv >> 2, wn = wv & 3;       // 2 x 4 wave grid; wave tile 128 x 64
  const int fr = lane & 15, fk = lane >> 4;

  // XCD-aware swizzle: 256 blocks, 256 % 8 == 0 -> bijective
  int bi = blockIdx.x;
  int swz = (bi & 7) * 32 + (bi >> 3);
  int brow = swz >> 4, bcol = swz & 15;

  const unsigned short* Abase = A + (size_t)brow * 256 * GK;
  const unsigned short* Bbase = B + (size_t)bcol * 256 * GK;

  // ---- read-side swizzled column byte within 64B row: fk*16 ^ (row-bit-3 << 5) ----
  const int cA = (fk * 16) ^ ((fr & 8) << 2);

  // ---- stage source permutation (derived from layout formula, verified bijective):
  //   lane writes LDS bytes [wv*1024 + l*8192 + lane*16, +16) which per the layout
  //   hold global (row = l*64 + (wv>>1)*16 + (lane>>2),
  //                kbyte = (wv&1)*64 + ((lane&3)*16 ^ (lane&32 ? 32 : 0)) .. +16)
  const int srow = (wv >> 1) * 16 + (lane >> 2);                 // + l*64
  const int skelt = ((wv & 1) * 64 + (((lane & 3) * 16) ^ ((lane & 32) ? 32 : 0))) >> 1;

  auto stage = [&](const unsigned short* gb, unsigned short* lb, int h, int kt) {
    const unsigned short* g = gb + ((size_t)h * 128) * GK + kt * 64 + skelt;
    char* lc = (char*)lb + wv * 1024 + lane * 16;
#pragma unroll
    for (int l = 0; l < 2; ++l)
      gload16(g + (size_t)(l * 64 + srow) * GK, lc + l * 8192);
  };

  f32x4 acc[8][4];
#pragma unroll
  for (int m = 0; m < 8; ++m)
#pragma unroll
    for (int n = 0; n < 4; ++n) acc[m][n] = (f32x4){0.f, 0.f, 0.f, 0.f};

  // ---- prologue: A(0) both halves, B(0) both halves, B(1) both halves ----
  stage(Abase, &sA[0][0][0], 0, 0);
  stage(Abase, &sA[0][1][0], 1, 0);
  stage(Bbase, &sB[0][0][0], 0, 0);
  stage(Bbase, &sB[0][1][0], 1, 0);
  stage(Bbase, &sB[1][0][0], 0, 1);
  stage(Bbase, &sB[1][1][0], 1, 1);
  VM4();            // A(0), B(0) landed; B(1) may remain in flight
  BAR();
  SCHED0();

  const int nsub = (wn & 1) * 4;       // B subtile-row base within half (rows (wn&1)*64..)

  // A frag LDS byte: m*2048 + kh*1024 + fr*64 + cA   (within sA[kbuf][wm])
  // B frag LDS byte: (nsub+n)*2048 + kh*1024 + fr*64 + cA   (within sB[kbuf][wn>>1])

#pragma unroll 1
  for (int i = 0; i < 32; ++i) {
    const int ktA1 = 2 * i + 1;                          // A kt1, staged ph1-2, read ph5
    const int ktN0 = (2 * i + 2 < 64) ? 2 * i + 2 : 63;  // next kt0 (B: ph3-4, A: ph5-6)
    const int ktN1 = (2 * i + 3 < 64) ? 2 * i + 3 : 63;  // next kt1 (B: ph7-8)

    short8 af[4][2], bf0[2][2], bf1[2][2];

    // ================= K-tile kt0 (kbuf 0), phases 1-4 =================
    {
      const char* bA = (const char*)&sA[0][wm][0];
      const char* bB = (const char*)&sB[0][wn >> 1][0];

      // -- ph1: read A m0-3 + B n0-1; stage A(kt1,h0) --
#pragma unroll
      for (int m = 0; m < 4; ++m)
#pragma unroll
        for (int kh = 0; kh < 2; ++kh)
          af[m][kh] = *(const short8*)(bA + m * 2048 + kh * 1024 + fr * 64 + cA);
#pragma unroll
      for (int n = 0; n < 2; ++n)
#pragma unroll
        for (int kh = 0; kh < 2; ++kh)
          bf0[n][kh] = *(const short8*)(bB + (nsub + n) * 2048 + kh * 1024 + fr * 64 + cA);
      stage(Abase, &sA[1][0][0], 0, ktA1);
      BAR(); LGKM0(); SCHED0(); PRIO1();
#pragma unroll
      for (int m = 0; m < 4; ++m)
#pragma unroll
        for (int n = 0; n < 2; ++n)
#pragma unroll
          for (int kh = 0; kh < 2; ++kh)
            acc[m][n] = __builtin_amdgcn_mfma_f32_16x16x32_bf16(af[m][kh], bf0[n][kh], acc[m][n], 0, 0, 0);
      PRIO0(); SCHED0(); BAR();

      // -- ph2: read B n2-3; stage A(kt1,h1) --
#pragma unroll
      for (int n = 0; n < 2; ++n)
#pragma unroll
        for (int kh = 0; kh < 2; ++kh)
          bf1[n][kh] = *(const short8*)(bB + (nsub + n + 2) * 2048 + kh * 1024 + fr * 64 + cA);
      stage(Abase, &sA[1][1][0], 1, ktA1);
      BAR(); LGKM0(); SCHED0(); PRIO1();
#pragma unroll
      for (int m = 0; m < 4; ++m)
#pragma unroll
        for (int n = 0; n < 2; ++n)
#pragma unroll
          for (int kh = 0; kh < 2; ++kh)
            acc[m][n + 2] = __builtin_amdgcn_mfma_f32_16x16x32_bf16(af[m][kh], bf1[n][kh], acc[m][n + 2], 0, 0, 0);
      PRIO0(); SCHED0(); BAR();

      // -- ph3: read A m4-7; stage B(ktN0,h0) [B kbuf0 dead after ph2 barrier] --
#pragma unroll
      for (int m = 0; m < 4; ++m)
#pragma unroll
        for (int kh = 0; kh < 2; ++kh)
          af[m][kh] = *(const short8*)(bA + (m + 4) * 2048 + kh * 1024 + fr * 64 + cA);
      stage(Bbase, &sB[0][0][0], 0, ktN0);
      BAR(); LGKM0(); SCHED0(); PRIO1();
#pragma unroll
      for (int m = 0; m < 4; ++m)
#pragma unroll
        for (int n = 0; n < 2; ++n)
#pragma unroll
          for (int kh = 0; kh < 2; ++kh)
            acc[m + 4][n + 2] = __builtin_amdgcn_mfma_f32_16x16x32_bf16(af[m][kh], bf1[n][kh], acc[m + 4][n + 2], 0, 0, 0);
      PRIO0(); SCHED0(); BAR();

      // -- ph4: no ds_reads; stage B(ktN0,h1); vmcnt(4) -> A(kt1) landed --
      stage(Bbase, &sB[0][1][0], 1, ktN0);
      BAR(); PRIO1();
#pragma unroll
      for (int m = 0; m < 4; ++m)
#pragma unroll
        for (int n = 0; n < 2; ++n)
#pragma unroll
          for (int kh = 0; kh < 2; ++kh)
            acc[m + 4][n] = __builtin_amdgcn_mfma_f32_16x16x32_bf16(af[m][kh], bf0[n][kh], acc[m + 4][n], 0, 0, 0);
      PRIO0(); SCHED0();
      VM4(); BAR(); SCHED0();
    }

    // ================= K-tile kt1 (kbuf 1), phases 5-8 =================
    {
      const char* bA = (const char*)&sA[1][wm][0];
      const char* bB = (const char*)&sB[1][wn >> 1][0];

      // -- ph5: read A m0-3 + B n0-1; stage A(ktN0,h0) [A kbuf0 dead after ph3] --
#pragma unroll
      for (int m = 0; m < 4; ++m)
#pragma unroll
        for (int kh = 0; kh < 2; ++kh)
          af[m][kh] = *(const short8*)(bA + m * 2048 + kh * 1024 + fr * 64 + cA);
#pragma unroll
      for (int n = 0; n < 2; ++n)
#pragma unroll
        for (int kh = 0; kh < 2; ++kh)
          bf0[n][kh] = *(const short8*)(bB + (nsub + n) * 2048 + kh * 1024 + fr * 64 + cA);
      stage(Abase, &sA[0][0][0], 0, ktN0);
      BAR(); LGKM0(); SCHED0(); PRIO1();
#pragma unroll
      for (int m = 0; m < 4; ++m)
#pragma unroll
        for (int n = 0; n < 2; ++n)
#pragma unroll
          for (int kh = 0; kh < 2; ++kh)
            acc[m][n] = __builtin_amdgcn_mfma_f32_16x16x32_bf16(af[m][kh], bf0[n][kh], acc[m][n], 0, 0, 0);
      PRIO0(); SCHED0(); BAR();

      // -- ph6: read B n2-3; stage A(ktN0,h1) --
#pragma unroll
      for (int n = 0; n < 2; ++n)
#pragma unroll
        for (int kh = 0; kh < 2; ++kh)
          bf1[n][kh] = *(const short8*)(bB + (nsub + n + 2) * 2048 + kh * 1024 + fr * 64 + cA);
      stage(Abase, &sA[0][1][0], 1, ktN0);
      BAR(); LGKM0(); SCHED0(); PRIO1();
#pragma unroll
      for (int m = 0; m < 4; ++m)
#pragma unroll
        for (int n = 0; n < 2; ++n)
#pragma unroll
          for (int kh = 0; kh < 2; ++kh)
            acc[m][n + 2] = __builtin_amdgcn_mfma_f32_16x16x32_bf16(af[m][kh], bf1[n][kh], acc[m][n + 2], 0, 0, 0);
      PRIO0(); SCHED0(); BAR();

      // -- ph7: read A m4-7; stage B(ktN1,h0) [B kbuf1 dead after ph6] --
#pragma unroll
      for (int m = 0; m < 4; ++m)
#pragma unroll
        for (int kh = 0; kh < 2; ++kh)
          af[m][kh] = *(const short8*)(bA + (m + 4) * 2048 + kh * 1024 + fr * 64 + cA);
      stage(Bbase, &sB[1][0][0], 0, ktN1);
      BAR(); LGKM0(); SCHED0(); PRIO1();
#pragma unroll
      for (int m = 0; m < 4; ++m)
#pragma unroll
        for (int n = 0; n < 2; ++n)
#pragma unroll
          for (int kh = 0; kh < 2; ++kh)
            acc[m + 4][n + 2] = __builtin_amdgcn_mfma_f32_16x16x32_bf16(af[m][kh], bf1[n][kh], acc[m + 4][n + 2], 0, 0, 0);
      PRIO0(); SCHED0(); BAR();

      // -- ph8: no ds_reads; stage B(ktN1,h1); vmcnt(4) -> A/B(ktN0) landed --
      stage(Bbase, &sB[1][1][0], 1, ktN1);
      BAR(); PRIO1();
#pragma unroll
      for (int m = 0; m < 4; ++m)
#pragma unroll
        for (int n = 0; n < 2; ++n)
#pragma unroll
          for (int kh = 0; kh < 2; ++kh)
            acc[m + 4][n] = __builtin_amdgcn_mfma_f32_16x16x32_bf16(af[m][kh], bf0[n][kh], acc[m + 4][n], 0, 0, 0);
      PRIO0(); SCHED0();
      VM4(); BAR(); SCHED0();
    }
  }

  // epilogue: verified C/D mapping: row = m*16 + fk*4 + j, col = n*16 + fr
  const int rbase = brow * 256 + wm * 128;
  const int cbase = bcol * 256 + wn * 64;
#pragma unroll
  for (int m = 0; m < 8; ++m)
#pragma unroll
    for (int n = 0; n < 4; ++n)
#pragma unroll
      for (int j = 0; j < 4; ++j) {
        int rr = rbase + m * 16 + fk * 4 + j;
        int cc = cbase + n * 16 + fr;
        C[(size_t)rr * GK + cc] = acc[m][n][j];
      }
}

// ---------------------------------------------------------------------------
extern "C" void kernel_launch(void* const* d_in, const int* in_sizes, int n_in,
                              void* d_out, int out_size, void* d_ws, size_t ws_size,
                              hipStream_t stream) {
  const float* x = (const float*)d_in[0];
  const float* W = (const float*)d_in[1];
  const float* lut = (const float*)d_in[2];
  float* out = (float*)d_out;

  unsigned short* xb = (unsigned short*)d_ws;                  // 32 MB bf16 x
  unsigned short* qb = xb + (size_t)4096 * 4096;               // 32 MB bf16 qweight

  prep_kernel<<<8192, 256, 0, stream>>>(x, W, lut, xb, qb);
  gemm_bt<<<256, 512, 0, stream>>>(xb, qb, out);
}

// Round 5
// 155.519 us; speedup vs baseline: 1.5797x; 1.0727x over previous
//
#include <hip/hip_runtime.h>
#include <hip/hip_fp16.h>
#include <stdint.h>

typedef __attribute__((ext_vector_type(4))) float f32x4;
typedef __attribute__((ext_vector_type(8))) short short8;

__device__ __forceinline__ unsigned short f2bf(float f) {
  unsigned int b = __float_as_uint(f);
  b = b + 0x7FFFu + ((b >> 16) & 1u);   // RNE
  return (unsigned short)(b >> 16);
}

#define CE(a, b) { float _lo = fminf((a), (b)), _hi = fmaxf((a), (b)); (a) = _lo; (b) = _hi; }

// Batcher odd-even merge of two ascending sorted 4-lists (x[0..3], x[4..7]) -> sorted 8
__device__ __forceinline__ void merge8(float x[8]) {
  CE(x[0], x[4]); CE(x[1], x[5]); CE(x[2], x[6]); CE(x[3], x[7]);
  CE(x[2], x[4]); CE(x[3], x[5]);
  CE(x[1], x[2]); CE(x[3], x[4]); CE(x[5], x[6]);
}

// ---------------------------------------------------------------------------
// Fused prep kernel: blocks 0..4095 = per-row NF4 quant+dequant of W -> qb,
//                    blocks 4096..8191 = x fp32 -> bf16 cvt
// ---------------------------------------------------------------------------
__global__ __launch_bounds__(256) void prep_kernel(const float* __restrict__ x,
                                                   const float* __restrict__ W,
                                                   const float* __restrict__ lut,
                                                   unsigned short* __restrict__ xb,
                                                   unsigned short* __restrict__ qb) {
  const int tid = threadIdx.x;

  if (blockIdx.x >= 4096) {
    // ---- cvt path ----
    int b = blockIdx.x - 4096;
    int base = b * 1024 + tid;   // float4 index
#pragma unroll
    for (int it = 0; it < 4; ++it) {
      int i = base + it * 256;
      f32x4 v = ((const f32x4*)x)[i];
      ushort4 u;
      u.x = f2bf(v[0]); u.y = f2bf(v[1]); u.z = f2bf(v[2]); u.w = f2bf(v[3]);
      ((ushort4*)xb)[i] = u;
    }
    return;
  }

  // ---- quant path ----
  const int C = 4096;
  const int row = blockIdx.x;
  const int lane = tid & 63;
  const int wv = tid >> 6;

  __shared__ float s_luth[16];   // fp16-rounded poles (dequant values)
  __shared__ float s_mid[15];    // decision midpoints on fp32 poles
  __shared__ float s_red[4][8];
  __shared__ float s_par[4];

  if (tid < 16) {
    float f = lut[tid];
    s_luth[tid] = __half2float(__float2half(f));  // .half() per reference
  }
  if (tid < 15) s_mid[tid] = 0.5f * (lut[tid] + lut[tid + 1]);

  const f32x4* Wp = (const f32x4*)(W + (size_t)row * C);
  f32x4 v[4];
#pragma unroll
  for (int i = 0; i < 4; ++i) v[i] = Wp[i * 256 + tid];

  // per-thread bottom-4 (ascending) and top-4 (ascending)
  float bot[4] = {__builtin_inff(), __builtin_inff(), __builtin_inff(), __builtin_inff()};
  float top[4] = {-__builtin_inff(), -__builtin_inff(), -__builtin_inff(), -__builtin_inff()};
#pragma unroll
  for (int i = 0; i < 4; ++i) {
#pragma unroll
    for (int j = 0; j < 4; ++j) {
      float f = v[i][j];
      bot[3] = fminf(bot[3], f); CE(bot[2], bot[3]); CE(bot[1], bot[2]); CE(bot[0], bot[1]);
      top[0] = fmaxf(top[0], f); CE(top[0], top[1]); CE(top[1], top[2]); CE(top[2], top[3]);
    }
  }

#pragma unroll
  for (int d = 1; d < 64; d <<= 1) {
    float xx[8];
#pragma unroll
    for (int j = 0; j < 4; ++j) { xx[j] = bot[j]; xx[4 + j] = __shfl_xor(bot[j], d); }
    merge8(xx);
#pragma unroll
    for (int j = 0; j < 4; ++j) bot[j] = xx[j];
#pragma unroll
    for (int j = 0; j < 4; ++j) { xx[j] = top[j]; xx[4 + j] = __shfl_xor(top[j], d); }
    merge8(xx);
#pragma unroll
    for (int j = 0; j < 4; ++j) top[j] = xx[4 + j];
  }

  if (lane == 0) {
#pragma unroll
    for (int j = 0; j < 4; ++j) { s_red[wv][j] = bot[j]; s_red[wv][4 + j] = top[j]; }
  }
  __syncthreads();

  if (tid == 0) {
    float a[8], b[8], m[8];
#pragma unroll
    for (int j = 0; j < 4; ++j) { a[j] = s_red[0][j]; a[4 + j] = s_red[1][j]; }
    merge8(a);
#pragma unroll
    for (int j = 0; j < 4; ++j) { b[j] = s_red[2][j]; b[4 + j] = s_red[3][j]; }
    merge8(b);
#pragma unroll
    for (int j = 0; j < 4; ++j) { m[j] = a[j]; m[4 + j] = b[j]; }
    merge8(m);
    float lower = m[2] + 0.0475f * (m[3] - m[2]);   // quantile 0.0005 -> idx 2.0475
#pragma unroll
    for (int j = 0; j < 4; ++j) { a[j] = s_red[0][4 + j]; a[4 + j] = s_red[1][4 + j]; }
    merge8(a);
#pragma unroll
    for (int j = 0; j < 4; ++j) { b[j] = s_red[2][4 + j]; b[4 + j] = s_red[3][4 + j]; }
    merge8(b);
#pragma unroll
    for (int j = 0; j < 4; ++j) { m[j] = a[4 + j]; m[4 + j] = b[4 + j]; }
    merge8(m);
    float upper = m[4] + 0.9525f * (m[5] - m[4]);   // quantile 0.9995 -> idx 4092.9525
    s_par[0] = lower; s_par[1] = upper;
  }
  __syncthreads();

  float lower = s_par[0], upper = s_par[1];

  float mn = __builtin_inff(), mx = -__builtin_inff();
#pragma unroll
  for (int i = 0; i < 4; ++i) {
#pragma unroll
    for (int j = 0; j < 4; ++j) {
      float f = v[i][j];
      bool outl = (f <= lower) || (f >= upper);
      if (!outl) { mn = fminf(mn, f); mx = fmaxf(mx, f); }
    }
  }
#pragma unroll
  for (int d = 1; d < 64; d <<= 1) {
    mn = fminf(mn, __shfl_xor(mn, d));
    mx = fmaxf(mx, __shfl_xor(mx, d));
  }
  if (lane == 0) { s_red[wv][0] = mn; s_red[wv][1] = mx; }
  __syncthreads();
  if (tid == 0) {
    float tmn = fminf(fminf(s_red[0][0], s_red[1][0]), fminf(s_red[2][0], s_red[3][0]));
    float tmx = fmaxf(fmaxf(s_red[0][1], s_red[1][1]), fmaxf(s_red[2][1], s_red[3][1]));
    s_par[2] = (tmx + tmn) * 0.5f;   // offset
    s_par[3] = (tmx - tmn) * 0.5f;   // rangeval
  }
  __syncthreads();
  float offset = s_par[2], range = s_par[3];
  float invr = 1.0f / range;

  unsigned short* outr = qb + (size_t)row * C;
#pragma unroll
  for (int i = 0; i < 4; ++i) {
    ushort4 o;
    unsigned short os[4];
#pragma unroll
    for (int j = 0; j < 4; ++j) {
      float f = v[i][j];
      bool outl = (f <= lower) || (f >= upper);
      float q;
      if (outl) {
        q = f;  // Q=0 pole -> weight passes through
      } else {
        // nearest pole via branchless binary search on midpoints.
        // strict '>' keeps the LOWER index on exact ties == argmin semantics.
        float ws = (f - offset) * invr;
        int bi = (ws > s_mid[7]) ? 8 : 0;
        bi += (ws > s_mid[bi + 3]) ? 4 : 0;
        bi += (ws > s_mid[bi + 1]) ? 2 : 0;
        bi += (ws > s_mid[bi]) ? 1 : 0;
        q = s_luth[bi] * range + offset;
      }
      if (!isfinite(q)) q = 0.0f;
      os[j] = f2bf(q);
    }
    o.x = os[0]; o.y = os[1]; o.z = os[2]; o.w = os[3];
    ((ushort4*)outr)[i * 256 + tid] = o;
  }
}

// ---------------------------------------------------------------------------
// GEMM: C[4096,4096] = A * B^T (bf16 in, fp32 out). m201 port, round 5:
// 256x256 tile, BK=64, 8 waves (2Mx4N), LDS = 2 kbuf x 2 rowhalf x (A,B) x 16KB.
// Subtiled st_16x32 layout (round 4, conflicts == 0):
//   lds_byte(row,kbyte) = (row>>4)*2048 + (kbyte>>6)*1024 + (row&15)*64
//                         + ((kbyte&63) ^ ((row&8)<<2))
// Round-5 change: 3 half-tiles in flight (vmcnt(6)), earliest-legal stage slots:
//   ph1: A(kt1,h1)                       [h0 staged in prev ph8]
//   ph3: B(ktN0,h0)                      [B kbuf0 free after ph2 barrier]
//   ph4: B(ktN0,h1) + A(ktN0,h0); VM6    [A kbuf0 free after ph3 barrier]
//   ph5: A(ktN0,h1)
//   ph7: B(ktN1,h0)                      [B kbuf1 free after ph6 barrier]
//   ph8: B(ktN1,h1) + A(ktN1,h0); VM6    [A kbuf1 free after ph7 barrier]
// VM6 at ph4: outstanding = {B(ktN0)h0,h1, A(ktN0)h0} = 6 loads -> A(kt1) landed.
// VM6 at ph8: outstanding = {B(ktN1)h0,h1, A(ktN1)h0} = 6 loads -> A/B(ktN0) landed.
// Every waited load now staged >=3 phases (~810+ cyc) before its deadline.
// ---------------------------------------------------------------------------
#define GK 4096

__device__ __forceinline__ void gload16(const void* gp, void* lp) {
  __builtin_amdgcn_global_load_lds(
      (const __attribute__((address_space(1))) unsigned int*)(uintptr_t)gp,
      (__attribute__((address_space(3))) unsigned int*)(unsigned int)(uintptr_t)lp,
      16, 0, 0);
}

#define BAR()    __builtin_amdgcn_s_barrier()
#define SCHED0() __builtin_amdgcn_sched_barrier(0)
#define LGKM0()  asm volatile("s_waitcnt lgkmcnt(0)" ::: "memory")
#define VM6()    asm volatile("s_waitcnt vmcnt(6)" ::: "memory")
#define PRIO1()  __builtin_amdgcn_s_setprio(1)
#define PRIO0()  __builtin_amdgcn_s_setprio(0)

__global__ __launch_bounds__(512, 2) void gemm_bt(const unsigned short* __restrict__ A,
                                                  const unsigned short* __restrict__ B,
                                                  float* __restrict__ C) {
  // [kbuf][rowhalf][16KB half-tile] ; total 128 KiB
  __shared__ __align__(16) unsigned short sA[2][2][8192];
  __shared__ __align__(16) unsigned short sB[2][2][8192];

  const int tid = threadIdx.x;
  const int lane = tid & 63;
  const int wv = tid >> 6;
  const int wm = wv >> 2, wn = wv & 3;       // 2 x 4 wave grid; wave tile 128 x 64
  const int fr = lane & 15, fk = lane >> 4;

  // XCD-aware swizzle: 256 blocks, 256 % 8 == 0 -> bijective
  int bi = blockIdx.x;
  int swz = (bi & 7) * 32 + (bi >> 3);
  int brow = swz >> 4, bcol = swz & 15;

  const unsigned short* Abase = A + (size_t)brow * 256 * GK;
  const unsigned short* Bbase = B + (size_t)bcol * 256 * GK;

  // read-side swizzled column byte within 64B row: fk*16 ^ (row-bit-3 << 5)
  const int cA = (fk * 16) ^ ((fr & 8) << 2);

  // stage source permutation (round 4, verified): LDS bytes [wv*1024+l*8192+lane*16)
  // hold global (row = l*64 + (wv>>1)*16 + (lane>>2),
  //              kbyte = (wv&1)*64 + ((lane&3)*16 ^ (lane&32 ? 32 : 0)))
  const int srow = (wv >> 1) * 16 + (lane >> 2);                 // + l*64
  const int skelt = ((wv & 1) * 64 + (((lane & 3) * 16) ^ ((lane & 32) ? 32 : 0))) >> 1;

  auto stage = [&](const unsigned short* gb, unsigned short* lb, int h, int kt) {
    const unsigned short* g = gb + ((size_t)h * 128) * GK + kt * 64 + skelt;
    char* lc = (char*)lb + wv * 1024 + lane * 16;
#pragma unroll
    for (int l = 0; l < 2; ++l)
      gload16(g + (size_t)(l * 64 + srow) * GK, lc + l * 8192);
  };

  f32x4 acc[8][4];
#pragma unroll
  for (int m = 0; m < 8; ++m)
#pragma unroll
    for (int n = 0; n < 4; ++n) acc[m][n] = (f32x4){0.f, 0.f, 0.f, 0.f};

  // ---- prologue: 7 half-tiles; VM6 -> A(0),B(0) landed; {B(1)h0,h1,A(1)h0} in flight
  stage(Abase, &sA[0][0][0], 0, 0);
  stage(Abase, &sA[0][1][0], 1, 0);
  stage(Bbase, &sB[0][0][0], 0, 0);
  stage(Bbase, &sB[0][1][0], 1, 0);
  stage(Bbase, &sB[1][0][0], 0, 1);
  stage(Bbase, &sB[1][1][0], 1, 1);
  stage(Abase, &sA[1][0][0], 0, 1);
  VM6();
  BAR();
  SCHED0();

  const int nsub = (wn & 1) * 4;       // B subtile-row base within rowhalf

#pragma unroll 1
  for (int i = 0; i < 32; ++i) {
    const int ktA1 = 2 * i + 1;                          // kbuf1 content this iteration
    const int ktN0 = (2 * i + 2 < 64) ? 2 * i + 2 : 63;  // next kbuf0 content
    const int ktN1 = (2 * i + 3 < 64) ? 2 * i + 3 : 63;  // next kbuf1 content

    short8 af[4][2], bf0[2][2], bf1[2][2];

    // ================= K-tile kt0 (kbuf 0), phases 1-4 =================
    {
      const char* bA = (const char*)&sA[0][wm][0];
      const char* bB = (const char*)&sB[0][wn >> 1][0];

      // -- ph1: read A m0-3 + B n0-1; stage A(kt1,h1) --
#pragma unroll
      for (int m = 0; m < 4; ++m)
#pragma unroll
        for (int kh = 0; kh < 2; ++kh)
          af[m][kh] = *(const short8*)(bA + m * 2048 + kh * 1024 + fr * 64 + cA);
#pragma unroll
      for (int n = 0; n < 2; ++n)
#pragma unroll
        for (int kh = 0; kh < 2; ++kh)
          bf0[n][kh] = *(const short8*)(bB + (nsub + n) * 2048 + kh * 1024 + fr * 64 + cA);
      stage(Abase, &sA[1][1][0], 1, ktA1);
      BAR(); LGKM0(); SCHED0(); PRIO1();
#pragma unroll
      for (int m = 0; m < 4; ++m)
#pragma unroll
        for (int n = 0; n < 2; ++n)
#pragma unroll
          for (int kh = 0; kh < 2; ++kh)
            acc[m][n] = __builtin_amdgcn_mfma_f32_16x16x32_bf16(af[m][kh], bf0[n][kh], acc[m][n], 0, 0, 0);
      PRIO0(); SCHED0(); BAR();

      // -- ph2: read B n2-3; no stage --
#pragma unroll
      for (int n = 0; n < 2; ++n)
#pragma unroll
        for (int kh = 0; kh < 2; ++kh)
          bf1[n][kh] = *(const short8*)(bB + (nsub + n + 2) * 2048 + kh * 1024 + fr * 64 + cA);
      BAR(); LGKM0(); SCHED0(); PRIO1();
#pragma unroll
      for (int m = 0; m < 4; ++m)
#pragma unroll
        for (int n = 0; n < 2; ++n)
#pragma unroll
          for (int kh = 0; kh < 2; ++kh)
            acc[m][n + 2] = __builtin_amdgcn_mfma_f32_16x16x32_bf16(af[m][kh], bf1[n][kh], acc[m][n + 2], 0, 0, 0);
      PRIO0(); SCHED0(); BAR();

      // -- ph3: read A m4-7; stage B(ktN0,h0) [B kbuf0 free after ph2 barrier] --
#pragma unroll
      for (int m = 0; m < 4; ++m)
#pragma unroll
        for (int kh = 0; kh < 2; ++kh)
          af[m][kh] = *(const short8*)(bA + (m + 4) * 2048 + kh * 1024 + fr * 64 + cA);
      stage(Bbase, &sB[0][0][0], 0, ktN0);
      BAR(); LGKM0(); SCHED0(); PRIO1();
#pragma unroll
      for (int m = 0; m < 4; ++m)
#pragma unroll
        for (int n = 0; n < 2; ++n)
#pragma unroll
          for (int kh = 0; kh < 2; ++kh)
            acc[m + 4][n + 2] = __builtin_amdgcn_mfma_f32_16x16x32_bf16(af[m][kh], bf1[n][kh], acc[m + 4][n + 2], 0, 0, 0);
      PRIO0(); SCHED0(); BAR();

      // -- ph4: no ds_reads; stage B(ktN0,h1) + A(ktN0,h0); VM6 -> A(kt1) landed --
      stage(Bbase, &sB[0][1][0], 1, ktN0);
      stage(Abase, &sA[0][0][0], 0, ktN0);
      BAR(); PRIO1();
#pragma unroll
      for (int m = 0; m < 4; ++m)
#pragma unroll
        for (int n = 0; n < 2; ++n)
#pragma unroll
          for (int kh = 0; kh < 2; ++kh)
            acc[m + 4][n] = __builtin_amdgcn_mfma_f32_16x16x32_bf16(af[m][kh], bf0[n][kh], acc[m + 4][n], 0, 0, 0);
      PRIO0(); SCHED0();
      VM6(); BAR(); SCHED0();
    }

    // ================= K-tile kt1 (kbuf 1), phases 5-8 =================
    {
      const char* bA = (const char*)&sA[1][wm][0];
      const char* bB = (const char*)&sB[1][wn >> 1][0];

      // -- ph5: read A m0-3 + B n0-1; stage A(ktN0,h1) --
#pragma unroll
      for (int m = 0; m < 4; ++m)
#pragma unroll
        for (int kh = 0; kh < 2; ++kh)
          af[m][kh] = *(const short8*)(bA + m * 2048 + kh * 1024 + fr * 64 + cA);
#pragma unroll
      for (int n = 0; n < 2; ++n)
#pragma unroll
        for (int kh = 0; kh < 2; ++kh)
          bf0[n][kh] = *(const short8*)(bB + (nsub + n) * 2048 + kh * 1024 + fr * 64 + cA);
      stage(Abase, &sA[0][1][0], 1, ktN0);
      BAR(); LGKM0(); SCHED0(); PRIO1();
#pragma unroll
      for (int m = 0; m < 4; ++m)
#pragma unroll
        for (int n = 0; n < 2; ++n)
#pragma unroll
          for (int kh = 0; kh < 2; ++kh)
            acc[m][n] = __builtin_amdgcn_mfma_f32_16x16x32_bf16(af[m][kh], bf0[n][kh], acc[m][n], 0, 0, 0);
      PRIO0(); SCHED0(); BAR();

      // -- ph6: read B n2-3; no stage --
#pragma unroll
      for (int n = 0; n < 2; ++n)
#pragma unroll
        for (int kh = 0; kh < 2; ++kh)
          bf1[n][kh] = *(const short8*)(bB + (nsub + n + 2) * 2048 + kh * 1024 + fr * 64 + cA);
      BAR(); LGKM0(); SCHED0(); PRIO1();
#pragma unroll
      for (int m = 0; m < 4; ++m)
#pragma unroll
        for (int n = 0; n < 2; ++n)
#pragma unroll
          for (int kh = 0; kh < 2; ++kh)
            acc[m][n + 2] = __builtin_amdgcn_mfma_f32_16x16x32_bf16(af[m][kh], bf1[n][kh], acc[m][n + 2], 0, 0, 0);
      PRIO0(); SCHED0(); BAR();

      // -- ph7: read A m4-7; stage B(ktN1,h0) [B kbuf1 free after ph6 barrier] --
#pragma unroll
      for (int m = 0; m < 4; ++m)
#pragma unroll
        for (int kh = 0; kh < 2; ++kh)
          af[m][kh] = *(const short8*)(bA + (m + 4) * 2048 + kh * 1024 + fr * 64 + cA);
      stage(Bbase, &sB[1][0][0], 0, ktN1);
      BAR(); LGKM0(); SCHED0(); PRIO1();
#pragma unroll
      for (int m = 0; m < 4; ++m)
#pragma unroll
        for (int n = 0; n < 2; ++n)
#pragma unroll
          for (int kh = 0; kh < 2; ++kh)
            acc[m + 4][n + 2] = __builtin_amdgcn_mfma_f32_16x16x32_bf16(af[m][kh], bf1[n][kh], acc[m + 4][n + 2], 0, 0, 0);
      PRIO0(); SCHED0(); BAR();

      // -- ph8: no ds_reads; stage B(ktN1,h1) + A(ktN1,h0); VM6 -> A/B(ktN0) landed --
      stage(Bbase, &sB[1][1][0], 1, ktN1);
      stage(Abase, &sA[1][0][0], 0, ktN1);
      BAR(); PRIO1();
#pragma unroll
      for (int m = 0; m < 4; ++m)
#pragma unroll
        for (int n = 0; n < 2; ++n)
#pragma unroll
          for (int kh = 0; kh < 2; ++kh)
            acc[m + 4][n] = __builtin_amdgcn_mfma_f32_16x16x32_bf16(af[m][kh], bf0[n][kh], acc[m + 4][n], 0, 0, 0);
      PRIO0(); SCHED0();
      VM6(); BAR(); SCHED0();
    }
  }

  // epilogue: verified C/D mapping: row = m*16 + fk*4 + j, col = n*16 + fr
  const int rbase = brow * 256 + wm * 128;
  const int cbase = bcol * 256 + wn * 64;
#pragma unroll
  for (int m = 0; m < 8; ++m)
#pragma unroll
    for (int n = 0; n < 4; ++n)
#pragma unroll
      for (int j = 0; j < 4; ++j) {
        int rr = rbase + m * 16 + fk * 4 + j;
        int cc = cbase + n * 16 + fr;
        C[(size_t)rr * GK + cc] = acc[m][n][j];
      }
}

// ---------------------------------------------------------------------------
extern "C" void kernel_launch(void* const* d_in, const int* in_sizes, int n_in,
                              void* d_out, int out_size, void* d_ws, size_t ws_size,
                              hipStream_t stream) {
  const float* x = (const float*)d_in[0];
  const float* W = (const float*)d_in[1];
  const float* lut = (const float*)d_in[2];
  float* out = (float*)d_out;

  unsigned short* xb = (unsigned short*)d_ws;                  // 32 MB bf16 x
  unsigned short* qb = xb + (size_t)4096 * 4096;               // 32 MB bf16 qweight

  prep_kernel<<<8192, 256, 0, stream>>>(x, W, lut, xb, qb);
  gemm_bt<<<256, 512, 0, stream>>>(xb, qb, out);
}